// Round 6
// baseline (103.673 us; speedup 1.0000x reference)
//
#include <hip/hip_runtime.h>

// loss[b] = (beta1 - beta2)^2 - intersection   (see reference)
//   true: (B,4,4) fp32; pred: (B,10,3) fp32, rows 0..3 used.
//
// R6 = R5 retry: non-temporal streaming loads/stores via clang ext_vector
// types (HIP_vector_type structs are rejected by __builtin_nontemporal_load).

typedef float vf4 __attribute__((ext_vector_type(4)));
typedef float vf2 __attribute__((ext_vector_type(2)));

__global__ __launch_bounds__(256) void boxloss_kernel(
    const float* __restrict__ T, const float* __restrict__ P,
    float* __restrict__ out, int B)
{
    int b = blockIdx.x * blockDim.x + threadIdx.x;
    if (b >= B) return;

    // ---- load true: 4x vf4, 64B-aligned per record, non-temporal ----
    float tmnx[4], tmny[4], tmxx[4], tmxy[4];
    const vf4* T4 = reinterpret_cast<const vf4*>(T) + (size_t)b * 4;
    #pragma unroll
    for (int i = 0; i < 4; ++i) {
        vf4 t = __builtin_nontemporal_load(&T4[i]);
        tmnx[i] = t.x; tmny[i] = t.y; tmxx[i] = t.z; tmxy[i] = t.w;
    }

    // ---- load pred[:4,:3]: 6x vf2 (8B-aligned), non-temporal ----
    const vf2* P2 = reinterpret_cast<const vf2*>(P + (size_t)b * 30);
    float f[12];
    #pragma unroll
    for (int k = 0; k < 6; ++k) {
        vf2 q = __builtin_nontemporal_load(&P2[k]);
        f[2 * k] = q.x; f[2 * k + 1] = q.y;
    }
    float pmnx[4], pmny[4], pmxx[4], pmxy[4];
    #pragma unroll
    for (int j = 0; j < 4; ++j) {
        float p0 = f[3 * j], p1 = f[3 * j + 1], p2 = f[3 * j + 2];
        float mn = fminf(p0, p2), mx = fmaxf(p0, p2);
        pmnx[j] = mn; pmxx[j] = mx; pmny[j] = p1; pmxy[j] = p1 + (mx - mn);
    }

    // ---- 4x4 reductions (symmetry-reduced betas) ----
    float inter = 0.f;
    #pragma unroll
    for (int i = 0; i < 4; ++i) {
        #pragma unroll
        for (int j = 0; j < 4; ++j) {
            float xo = fmaxf(0.f, fminf(tmxx[i], pmxx[j]) - fmaxf(tmnx[i], pmnx[j]));
            float yo = fmaxf(0.f, fminf(tmxy[i], pmxy[j]) - fmaxf(tmny[i], pmny[j]));
            inter += xo * yo;
        }
    }
    float b1 = 0.f, b2 = 0.f;
    #pragma unroll
    for (int i = 0; i < 4; ++i) {
        float w1 = fmaxf(0.f, tmxx[i] - tmnx[i]);
        float h1 = fmaxf(0.f, tmxy[i] - tmny[i]);
        float a1 = w1 * h1;
        float w2 = pmxx[i] - pmnx[i];
        float h2 = pmxy[i] - pmny[i];
        float a2 = w2 * h2;
        b1 += a1 * a1;
        b2 += a2 * a2;
    }
    #pragma unroll
    for (int i = 0; i < 4; ++i) {
        #pragma unroll
        for (int j = i + 1; j < 4; ++j) {
            float x1 = fmaxf(0.f, fminf(tmxx[i], tmxx[j]) - fmaxf(tmnx[i], tmnx[j]));
            float y1 = fmaxf(0.f, fminf(tmxy[i], tmxy[j]) - fmaxf(tmny[i], tmny[j]));
            b1 += 2.f * (x1 * y1);
            float x2 = fmaxf(0.f, fminf(pmxx[i], pmxx[j]) - fmaxf(pmnx[i], pmnx[j]));
            float y2 = fmaxf(0.f, fminf(pmxy[i], pmxy[j]) - fmaxf(pmny[i], pmny[j]));
            b2 += 2.f * (x2 * y2);
        }
    }
    float d = b1 - b2;
    float loss = d * d - inter;

    __builtin_nontemporal_store(loss, &out[b]);
}

extern "C" void kernel_launch(void* const* d_in, const int* in_sizes, int n_in,
                              void* d_out, int out_size, void* d_ws, size_t ws_size,
                              hipStream_t stream)
{
    const float* T = (const float*)d_in[0];   // true: B*16 floats
    const float* P = (const float*)d_in[1];   // pred: B*30 floats
    float* out = (float*)d_out;               // B floats
    int B = in_sizes[0] / 16;

    int block = 256;
    int grid = (B + block - 1) / block;
    boxloss_kernel<<<grid, block, 0, stream>>>(T, P, out, B);
}

// Round 7
// 63.829 us; speedup vs baseline: 1.6242x; 1.6242x over previous
//
#include <hip/hip_runtime.h>

// loss[b] = (beta1 - beta2)^2 - intersection   (see reference)
//   true: (B,4,4) fp32; pred: (B,10,3) fp32, rows 0..3 used.
//
// R7 = R4 (per-wave LDS staging, perfectly coalesced float4 global reads)
//      + NON-TEMPORAL on those reads (clean cache-policy test: every byte of
//      every line is consumed by exactly one load instr, so nt costs no reuse)
//      + nt store of out.

typedef float vf4 __attribute__((ext_vector_type(4)));

__device__ __forceinline__ float record_loss(
    const float tmnx[4], const float tmny[4], const float tmxx[4], const float tmxy[4],
    const float pf[12])
{
    float pmnx[4], pmny[4], pmxx[4], pmxy[4];
    #pragma unroll
    for (int j = 0; j < 4; ++j) {
        float p0 = pf[3 * j], p1 = pf[3 * j + 1], p2 = pf[3 * j + 2];
        float mn = fminf(p0, p2), mx = fmaxf(p0, p2);
        pmnx[j] = mn; pmxx[j] = mx; pmny[j] = p1; pmxy[j] = p1 + (mx - mn);
    }

    float inter = 0.f;
    #pragma unroll
    for (int i = 0; i < 4; ++i) {
        #pragma unroll
        for (int j = 0; j < 4; ++j) {
            float xo = fmaxf(0.f, fminf(tmxx[i], pmxx[j]) - fmaxf(tmnx[i], pmnx[j]));
            float yo = fmaxf(0.f, fminf(tmxy[i], pmxy[j]) - fmaxf(tmny[i], pmny[j]));
            inter += xo * yo;
        }
    }

    float b1 = 0.f, b2 = 0.f;
    #pragma unroll
    for (int i = 0; i < 4; ++i) {
        float w1 = fmaxf(0.f, tmxx[i] - tmnx[i]);
        float h1 = fmaxf(0.f, tmxy[i] - tmny[i]);
        float a1 = w1 * h1;
        float w2 = pmxx[i] - pmnx[i];
        float h2 = pmxy[i] - pmny[i];
        float a2 = w2 * h2;
        b1 += a1 * a1;
        b2 += a2 * a2;
    }
    #pragma unroll
    for (int i = 0; i < 4; ++i) {
        #pragma unroll
        for (int j = i + 1; j < 4; ++j) {
            float x1 = fmaxf(0.f, fminf(tmxx[i], tmxx[j]) - fmaxf(tmnx[i], tmnx[j]));
            float y1 = fmaxf(0.f, fminf(tmxy[i], tmxy[j]) - fmaxf(tmny[i], tmny[j]));
            b1 += 2.f * (x1 * y1);
            float x2 = fmaxf(0.f, fminf(pmxx[i], pmxx[j]) - fmaxf(pmnx[i], pmnx[j]));
            float y2 = fmaxf(0.f, fminf(pmxy[i], pmxy[j]) - fmaxf(pmny[i], pmny[j]));
            b2 += 2.f * (x2 * y2);
        }
    }
    float d = b1 - b2;
    return d * d - inter;
}

__global__ __launch_bounds__(256) void boxloss_kernel(
    const float* __restrict__ T, const float* __restrict__ P,
    float* __restrict__ out, int B)
{
    __shared__ vf4   sT[4][256];   // 16 KiB : true, xor-swizzled per wave
    __shared__ float sP[4][1920];  // 30 KiB : pred, linear per wave

    const int t = threadIdx.x;
    const int w = t >> 6;   // wave in block
    const int l = t & 63;   // lane
    const long long waveBase = (long long)blockIdx.x * 256 + (w << 6);

    // ---- stage true: 4 contiguous float4 per lane, non-temporal ----
    {
        const vf4* T4 = reinterpret_cast<const vf4*>(T);
        const long long base = waveBase << 2;
        const long long maxI = ((long long)B << 2) - 1;
        #pragma unroll
        for (int k = 0; k < 4; ++k) {
            int s = (k << 6) + l;                 // 0..255
            long long gi = base + s; if (gi > maxI) gi = maxI;
            int p = s ^ ((s >> 3) & 7);
            vf4 v = __builtin_nontemporal_load(&T4[gi]);
            sT[w][p] = v;
        }
    }
    // ---- stage pred: 480 contiguous float4 per wave, non-temporal ----
    {
        const vf4* P4 = reinterpret_cast<const vf4*>(P);
        const long long base = (waveBase >> 1) * 15;
        const long long maxI = ((long long)B >> 1) * 15 - 1;
        vf4* sPw = reinterpret_cast<vf4*>(sP[w]);
        #pragma unroll
        for (int k = 0; k < 8; ++k) {
            int s = (k << 6) + l;                 // 0..511
            if (s < 480) {
                long long gi = base + s; if (gi > maxI) gi = maxI;
                vf4 v = __builtin_nontemporal_load(&P4[gi]);
                sPw[s] = v;
            }
        }
    }

    __syncthreads();

    // ---- gather my record ----
    float tmnx[4], tmny[4], tmxx[4], tmxy[4];
    #pragma unroll
    for (int k = 0; k < 4; ++k) {
        int s = (l << 2) + k;
        int p = s ^ ((s >> 3) & 7);
        vf4 v = sT[w][p];
        tmnx[k] = v.x; tmny[k] = v.y; tmxx[k] = v.z; tmxy[k] = v.w;
    }
    float pf[12];
    {
        const float2* pp = reinterpret_cast<const float2*>(sP[w] + 30 * l);
        #pragma unroll
        for (int j = 0; j < 6; ++j) {
            float2 v = pp[j];
            pf[2 * j] = v.x; pf[2 * j + 1] = v.y;
        }
    }

    float loss = record_loss(tmnx, tmny, tmxx, tmxy, pf);

    long long b = waveBase + l;
    if (b < B) __builtin_nontemporal_store(loss, &out[b]);
}

extern "C" void kernel_launch(void* const* d_in, const int* in_sizes, int n_in,
                              void* d_out, int out_size, void* d_ws, size_t ws_size,
                              hipStream_t stream)
{
    const float* T = (const float*)d_in[0];   // true: B*16 floats
    const float* P = (const float*)d_in[1];   // pred: B*30 floats
    float* out = (float*)d_out;               // B floats
    int B = in_sizes[0] / 16;

    int grid = (B + 255) / 256;
    boxloss_kernel<<<grid, 256, 0, stream>>>(T, P, out, B);
}